// Round 11
// baseline (115.642 us; speedup 1.0000x reference)
//
#include <hip/hip_runtime.h>
#include <hip/hip_fp16.h>
#include <math.h>

// MonotoneFeatureTransform: rational-quadratic spline per feature + batch standardize.
// B=131072, F=256, K=16. f32 in/out.
// pass1: R6/R10 frame (FTB=32, SLOTB=8, batch-8, bin-major LDS [16][32] float4 = 0
//   conflicts, lb(256,6)). R11 delta: 4-level LDS binary search for the bin index
//   (knots in LDS knT[15][32], bank = lane -> conflict-free; selects are inline
//   consts so no R9-style nested-ternary codegen collapse). Frees 15 knot VGPRs.
//   BANNED (measured): register-knot nested-ternary binsearch (R9: VGPR 24, 177us),
//   lb(256,8)/plain-lb (R4/R7/R8: VGPR 24 collapse).
// pass2: streaming standardize from f16 spill.

#define FEAT 256
#define KBINS 16
#define BATCH 131072
#define BOUNDF 5.0f
#define MIN_Df 1e-3f
#define MIN_BWf 1e-3f
#define MIN_BHf 1e-3f
#define EPSF 1e-8f

#define FTB 32                 // features per tile
#define FT_TILES 8
#define SLOTB 8                // row slots per block (256 thr / 32 feat)
#define RBB 256                // row-blocks
#define ROWS_PB (BATCH / RBB)  // 512 rows per block
#define ITERB (ROWS_PB / SLOTB) // 64 rows per thread

// Table region, float offsets relative to `tab`.
#define R_P0   0                    // [16][256] float4: cw0*binv, binv, h*delta, h*d0
#define R_P1   16384                // [16][256] float4: dsum, delta, ch0, pad
#define R_KN   32768                // [15][256] interior knots (cw[1..15])
#define R_MEAN 36608                // [256]
#define R_ISTD 36864                // [256]
#define R_PS   37120                // [2048][32] partial sums
#define R_PS2  (R_PS + 2048 * 32)   // [2048][32] partial sumsq
#define TAB_FLOATS (R_PS2 + 2048 * 32)
#define S_ELEMS ((size_t)BATCH * FEAT)
#define S_FLOATS (S_ELEMS / 2)

__global__ __launch_bounds__(256) void k_params(const float* __restrict__ uw,
                                                const float* __restrict__ uh,
                                                const float* __restrict__ ud,
                                                float* __restrict__ tab) {
    int f = threadIdx.x;
    float cw[17], ch[17], dv[17];
    {
        float u[KBINS];
#pragma unroll
        for (int j = 0; j < KBINS; j++) u[j] = uw[f * KBINS + j];
        float m = u[0];
#pragma unroll
        for (int j = 1; j < KBINS; j++) m = fmaxf(m, u[j]);
        float ssum = 0.f;
#pragma unroll
        for (int j = 0; j < KBINS; j++) { u[j] = expf(u[j] - m); ssum += u[j]; }
        float inv = 1.0f / ssum;
        float cum = 0.f;
        cw[0] = -BOUNDF;
#pragma unroll
        for (int j = 1; j < KBINS; j++) {
            float wj = MIN_BWf + (1.0f - MIN_BWf * (float)KBINS) * (u[j - 1] * inv);
            cum += wj;
            cw[j] = 2.0f * BOUNDF * cum - BOUNDF;
        }
        cw[KBINS] = BOUNDF;
    }
    {
        float u[KBINS];
#pragma unroll
        for (int j = 0; j < KBINS; j++) u[j] = uh[f * KBINS + j];
        float m = u[0];
#pragma unroll
        for (int j = 1; j < KBINS; j++) m = fmaxf(m, u[j]);
        float ssum = 0.f;
#pragma unroll
        for (int j = 0; j < KBINS; j++) { u[j] = expf(u[j] - m); ssum += u[j]; }
        float inv = 1.0f / ssum;
        float cum = 0.f;
        ch[0] = -BOUNDF;
#pragma unroll
        for (int j = 1; j < KBINS; j++) {
            float wj = MIN_BHf + (1.0f - MIN_BHf * (float)KBINS) * (u[j - 1] * inv);
            cum += wj;
            ch[j] = 2.0f * BOUNDF * cum - BOUNDF;
        }
        ch[KBINS] = BOUNDF;
    }
    {
        dv[0] = 1.0f;
        dv[KBINS] = 1.0f;
#pragma unroll
        for (int j = 1; j < KBINS; j++) {
            float v = ud[f * (KBINS - 1) + (j - 1)];
            float sp = fmaxf(v, 0.0f) + log1pf(expf(-fabsf(v))); // stable softplus
            dv[j] = MIN_Df + sp;
        }
    }
    // interior knots, feature-minor for coalesced reads
#pragma unroll
    for (int j = 0; j < 15; j++) tab[R_KN + j * 256 + f] = cw[j + 1];
    // packed per-bin params, BIN-MAJOR: [bin][feature]
    float4* P0g = (float4*)(tab + R_P0);
    float4* P1g = (float4*)(tab + R_P1);
#pragma unroll
    for (int i = 0; i < KBINS; i++) {
        float w = cw[i + 1] - cw[i];
        float binv = 1.0f / w;
        float hb = ch[i + 1] - ch[i];
        float delta = hb * binv;
        float4 p0, p1;
        p0.x = cw[i] * binv;
        p0.y = binv;
        p0.z = hb * delta;
        p0.w = hb * dv[i];
        p1.x = dv[i] + dv[i + 1] - 2.0f * delta;
        p1.y = delta;
        p1.z = ch[i];
        p1.w = 0.0f;
        P0g[i * 256 + f] = p0;
        P1g[i * 256 + f] = p1;
    }
}

// 4-level LDS binary search + rational-quadratic eval.
// sP0/sP1 bin-major [16][32]; knT [15][32] (knT[j][l] = cw[j+1] of feature l).
// Level s tests xn >= cw[idx+s] == knT[idx+s-1][l]; equivalent to the linear count.
__device__ __forceinline__ float eval_rq(float xv, float a, float nb,
                                         const float4* __restrict__ sP0,
                                         const float4* __restrict__ sP1,
                                         const float* __restrict__ knT, int l) {
    float xn = fmaf(xv, a, nb);
    int idx = 0;
#pragma unroll
    for (int s = 8; s >= 1; s >>= 1) {
        float kv = knT[(idx + s - 1) * 32 + l];
        idx += (xn >= kv) ? s : 0;
    }
    int o = (idx << 5) | l;
    float4 p0 = sP0[o];
    float4 p1 = sP1[o];
    float th = fmaf(xn, p0.y, -p0.x);
    float th2 = th * th;
    float t1m = th - th2;
    float numer = fmaf(p0.z, th2, p0.w * t1m);
    float denom = fmaf(p1.x, t1m, p1.y);
    float s = fmaf(numer, __builtin_amdgcn_rcpf(denom), p1.z);
    return (fabsf(xn) < BOUNDF) ? s : xn;
}

template <bool STORE_S>
__global__ __launch_bounds__(256, 6) void k_pass1(const float* __restrict__ X,
                                                  const float* __restrict__ shiftp,
                                                  const float* __restrict__ scalep,
                                                  float* __restrict__ tab,
                                                  unsigned short* __restrict__ S) {
    __shared__ float4 sP0[16 * FTB];
    __shared__ float4 sP1[16 * FTB];
    __shared__ float knT[15 * FTB];
    __shared__ float red[2][SLOTB][FTB];
    int t = threadIdx.x;
    int rb = blockIdx.x, ft = blockIdx.y;
    const float4* P0g = (const float4*)(tab + R_P0);
    const float4* P1g = (const float4*)(tab + R_P1);
    for (int s = t; s < 16 * FTB; s += 256) {
        int bin = s >> 5, li = s & 31;
        sP0[s] = P0g[bin * 256 + ft * FTB + li];
        sP1[s] = P1g[bin * 256 + ft * FTB + li];
    }
    if (t < 15 * FTB - 256) {
        int s2 = t + 256;
        knT[s2] = tab[R_KN + (s2 >> 5) * 256 + ft * FTB + (s2 & 31)];
    }
    knT[t < 15 * FTB ? t : 0] = tab[R_KN + ((t < 15 * FTB ? t : 0) >> 5) * 256 + ft * FTB + (t & 31)];
    int l = t & 31, slot = t >> 5;
    int f = ft * FTB + l;
    float a = 1.0f / scalep[f];
    float nb = -shiftp[f] * a;
    __syncthreads();
    size_t base = ((size_t)rb * ROWS_PB + slot) * FEAT + f;
    const float* Xp = X + base;
    unsigned short* Sp = STORE_S ? (S + base) : nullptr;
    float sum = 0.f, sumsq = 0.f;
    for (int r = 0; r < ITERB; r += 8) {
        float xv[8];
#pragma unroll
        for (int i = 0; i < 8; i++) xv[i] = Xp[i * SLOTB * FEAT];
        Xp += 8 * SLOTB * FEAT;
        float sv[8];
#pragma unroll
        for (int i = 0; i < 8; i++) sv[i] = eval_rq(xv[i], a, nb, sP0, sP1, knT, l);
        if (STORE_S) {
#pragma unroll
            for (int i = 0; i < 8; i++) Sp[i * SLOTB * FEAT] = __half_as_ushort(__float2half(sv[i]));
            Sp += 8 * SLOTB * FEAT;
        }
#pragma unroll
        for (int i = 0; i < 8; i++) { sum += sv[i]; sumsq = fmaf(sv[i], sv[i], sumsq); }
    }
    red[0][slot][l] = sum;
    red[1][slot][l] = sumsq;
    __syncthreads();
    if (t < FTB) {
        float v = 0.f;
#pragma unroll
        for (int s2i = 0; s2i < SLOTB; s2i++) v += red[0][s2i][t];
        tab[R_PS + (ft * RBB + rb) * FTB + t] = v;
    } else if (t < 2 * FTB) {
        int u = t - FTB;
        float v = 0.f;
#pragma unroll
        for (int s2i = 0; s2i < SLOTB; s2i++) v += red[1][s2i][u];
        tab[R_PS2 + (ft * RBB + rb) * FTB + u] = v;
    }
}

__global__ __launch_bounds__(256) void k_reduce(float* __restrict__ tab) {
    int f = blockIdx.x;
    int ft = f >> 5, l = f & 31;
    int t = threadIdx.x;
    __shared__ float r1[256], r2[256];
    r1[t] = tab[R_PS + (ft * RBB + t) * FTB + l];
    r2[t] = tab[R_PS2 + (ft * RBB + t) * FTB + l];
    __syncthreads();
    for (int off = 128; off > 0; off >>= 1) {
        if (t < off) { r1[t] += r1[t + off]; r2[t] += r2[t + off]; }
        __syncthreads();
    }
    if (t == 0) {
        float mean = r1[0] * (1.0f / (float)BATCH);
        float var = r2[0] * (1.0f / (float)BATCH) - mean * mean;
        var = fmaxf(var, 0.0f);
        tab[R_MEAN + f] = mean;
        tab[R_ISTD + f] = 1.0f / sqrtf(var + EPSF);
    }
}

// Streaming standardize: z = s*istd - mean*istd, s from f16 buffer.
__global__ __launch_bounds__(256, 8) void k_pass2_stream(const unsigned short* __restrict__ S,
                                                         const float* __restrict__ tab,
                                                         float* __restrict__ Z) {
    int gid = blockIdx.x * 256 + threadIdx.x;   // 524288 threads
    int fg = gid & 31;                          // feature-group: features fg*8 .. fg*8+7
    int rs = gid >> 5;                          // row-slot: rows rs*8 .. rs*8+7
    const float* meanp = tab + R_MEAN + fg * 8;
    const float* istdp = tab + R_ISTD + fg * 8;
    float istd[8], nmi[8];
#pragma unroll
    for (int j = 0; j < 8; j++) {
        float m = meanp[j];
        float is = istdp[j];
        istd[j] = is;
        nmi[j] = -m * is;
    }
    size_t idx = (size_t)rs * 8 * FEAT + fg * 8;
#pragma unroll
    for (int r = 0; r < 8; r++) {
        uint4 sv = *(const uint4*)(S + idx);
        float2 f0 = __half22float2(*(const __half2*)&sv.x);
        float2 f1 = __half22float2(*(const __half2*)&sv.y);
        float2 f2 = __half22float2(*(const __half2*)&sv.z);
        float2 f3 = __half22float2(*(const __half2*)&sv.w);
        float z0 = fmaf(f0.x, istd[0], nmi[0]);
        float z1 = fmaf(f0.y, istd[1], nmi[1]);
        float z2 = fmaf(f1.x, istd[2], nmi[2]);
        float z3 = fmaf(f1.y, istd[3], nmi[3]);
        float z4 = fmaf(f2.x, istd[4], nmi[4]);
        float z5 = fmaf(f2.y, istd[5], nmi[5]);
        float z6 = fmaf(f3.x, istd[6], nmi[6]);
        float z7 = fmaf(f3.y, istd[7], nmi[7]);
        float4* Zp = (float4*)(Z + idx);
        Zp[0] = make_float4(z0, z1, z2, z3);
        Zp[1] = make_float4(z4, z5, z6, z7);
        idx += FEAT;
    }
}

// Fallback pass2: recompute spline (when ws can't hold S).
__global__ __launch_bounds__(256, 6) void k_pass2_eval(const float* __restrict__ X,
                                                       const float* __restrict__ shiftp,
                                                       const float* __restrict__ scalep,
                                                       const float* __restrict__ tab,
                                                       float* __restrict__ Z) {
    __shared__ float4 sP0[16 * FTB];
    __shared__ float4 sP1[16 * FTB];
    __shared__ float knT[15 * FTB];
    int t = threadIdx.x;
    int rb = blockIdx.x, ft = blockIdx.y;
    const float4* P0g = (const float4*)(tab + R_P0);
    const float4* P1g = (const float4*)(tab + R_P1);
    for (int s = t; s < 16 * FTB; s += 256) {
        int bin = s >> 5, li = s & 31;
        sP0[s] = P0g[bin * 256 + ft * FTB + li];
        sP1[s] = P1g[bin * 256 + ft * FTB + li];
    }
    for (int s = t; s < 15 * FTB; s += 256)
        knT[s] = tab[R_KN + (s >> 5) * 256 + ft * FTB + (s & 31)];
    int l = t & 31, slot = t >> 5;
    int f = ft * FTB + l;
    float a = 1.0f / scalep[f];
    float nb = -shiftp[f] * a;
    float mean = tab[R_MEAN + f];
    float istd = tab[R_ISTD + f];
    __syncthreads();
    size_t base = ((size_t)rb * ROWS_PB + slot) * FEAT + f;
    const float* Xp = X + base;
    float* Zp = Z + base;
    for (int r = 0; r < ITERB; r += 4) {
        float x0 = Xp[0 * SLOTB * FEAT];
        float x1 = Xp[1 * SLOTB * FEAT];
        float x2 = Xp[2 * SLOTB * FEAT];
        float x3 = Xp[3 * SLOTB * FEAT];
        Xp += 4 * SLOTB * FEAT;
        float s0 = eval_rq(x0, a, nb, sP0, sP1, knT, l);
        float s1 = eval_rq(x1, a, nb, sP0, sP1, knT, l);
        float s2 = eval_rq(x2, a, nb, sP0, sP1, knT, l);
        float s3 = eval_rq(x3, a, nb, sP0, sP1, knT, l);
        Zp[0 * SLOTB * FEAT] = (s0 - mean) * istd;
        Zp[1 * SLOTB * FEAT] = (s1 - mean) * istd;
        Zp[2 * SLOTB * FEAT] = (s2 - mean) * istd;
        Zp[3 * SLOTB * FEAT] = (s3 - mean) * istd;
        Zp += 4 * SLOTB * FEAT;
    }
}

extern "C" void kernel_launch(void* const* d_in, const int* in_sizes, int n_in,
                              void* d_out, int out_size, void* d_ws, size_t ws_size,
                              hipStream_t stream) {
    const float* x     = (const float*)d_in[0];
    const float* uw    = (const float*)d_in[1];
    const float* uh    = (const float*)d_in[2];
    const float* ud    = (const float*)d_in[3];
    const float* shift = (const float*)d_in[4];
    const float* scale = (const float*)d_in[5];
    float* out = (float*)d_out;
    float* ws  = (float*)d_ws;

    size_t need = (S_FLOATS + (size_t)TAB_FLOATS) * sizeof(float);
    bool useS = ws_size >= need;
    float* tab = ws + (useS ? S_FLOATS : 0);
    unsigned short* S = (unsigned short*)ws;

    k_params<<<1, 256, 0, stream>>>(uw, uh, ud, tab);
    if (useS) {
        k_pass1<true><<<dim3(RBB, FT_TILES), 256, 0, stream>>>(x, shift, scale, tab, S);
        k_reduce<<<FEAT, 256, 0, stream>>>(tab);
        k_pass2_stream<<<2048, 256, 0, stream>>>(S, tab, out);
    } else {
        k_pass1<false><<<dim3(RBB, FT_TILES), 256, 0, stream>>>(x, shift, scale, tab, nullptr);
        k_reduce<<<FEAT, 256, 0, stream>>>(tab);
        k_pass2_eval<<<dim3(RBB, FT_TILES), 256, 0, stream>>>(x, shift, scale, tab, out);
    }
}

// Round 12
// 113.173 us; speedup vs baseline: 1.0218x; 1.0218x over previous
//
#include <hip/hip_runtime.h>
#include <hip/hip_fp16.h>
#include <math.h>

// MonotoneFeatureTransform: rational-quadratic spline per feature + batch standardize.
// B=131072, F=256, K=16. f32 in/out.
// pass1: R10 frame (FTB=32, SLOTB=8, batch-8, bin-major LDS [16][32] float4 = 0
//   conflicts, lb(256,6), f16 spill). R12 delta: even/odd knot split scan —
//   7 register compares (cw[2,4..14]) give pair index p; one conflict-free LDS read
//   knO[p][lane] (cw[2p+1], bank=lane) + 1 compare gives the low bit.
//   17 VALU + 1 LDS vs 30 VALU. Straight-line cmp/add only.
// BANNED (measured): nested-ternary select trees (R9: VGPR-collapse 24/177us),
//   lb(256,8)/plain-lb (R4/R7/R8 collapse), multi-level dependent LDS search
//   (R11: latency chain, VALU 32%, 88us).
// pass2: streaming standardize from f16 spill.

#define FEAT 256
#define KBINS 16
#define BATCH 131072
#define BOUNDF 5.0f
#define MIN_Df 1e-3f
#define MIN_BWf 1e-3f
#define MIN_BHf 1e-3f
#define EPSF 1e-8f

#define FTB 32                 // features per tile
#define FT_TILES 8
#define SLOTB 8                // row slots per block (256 thr / 32 feat)
#define RBB 256                // row-blocks
#define ROWS_PB (BATCH / RBB)  // 512 rows per block
#define ITERB (ROWS_PB / SLOTB) // 64 rows per thread

// Table region, float offsets relative to `tab`.
#define R_P0   0                    // [16][256] float4: cw0*binv, binv, h*delta, h*d0
#define R_P1   16384                // [16][256] float4: dsum, delta, ch0, pad
#define R_KN   32768                // [7][256] even knots cw[2,4..14] | [8][256] odd knots cw[1,3..15]
#define R_MEAN 36608                // [256]
#define R_ISTD 36864                // [256]
#define R_PS   37120                // [2048][32] partial sums
#define R_PS2  (R_PS + 2048 * 32)   // [2048][32] partial sumsq
#define TAB_FLOATS (R_PS2 + 2048 * 32)
#define S_ELEMS ((size_t)BATCH * FEAT)
#define S_FLOATS (S_ELEMS / 2)

__global__ __launch_bounds__(256) void k_params(const float* __restrict__ uw,
                                                const float* __restrict__ uh,
                                                const float* __restrict__ ud,
                                                float* __restrict__ tab) {
    int f = threadIdx.x;
    float cw[17], ch[17], dv[17];
    {
        float u[KBINS];
#pragma unroll
        for (int j = 0; j < KBINS; j++) u[j] = uw[f * KBINS + j];
        float m = u[0];
#pragma unroll
        for (int j = 1; j < KBINS; j++) m = fmaxf(m, u[j]);
        float ssum = 0.f;
#pragma unroll
        for (int j = 0; j < KBINS; j++) { u[j] = expf(u[j] - m); ssum += u[j]; }
        float inv = 1.0f / ssum;
        float cum = 0.f;
        cw[0] = -BOUNDF;
#pragma unroll
        for (int j = 1; j < KBINS; j++) {
            float wj = MIN_BWf + (1.0f - MIN_BWf * (float)KBINS) * (u[j - 1] * inv);
            cum += wj;
            cw[j] = 2.0f * BOUNDF * cum - BOUNDF;
        }
        cw[KBINS] = BOUNDF;
    }
    {
        float u[KBINS];
#pragma unroll
        for (int j = 0; j < KBINS; j++) u[j] = uh[f * KBINS + j];
        float m = u[0];
#pragma unroll
        for (int j = 1; j < KBINS; j++) m = fmaxf(m, u[j]);
        float ssum = 0.f;
#pragma unroll
        for (int j = 0; j < KBINS; j++) { u[j] = expf(u[j] - m); ssum += u[j]; }
        float inv = 1.0f / ssum;
        float cum = 0.f;
        ch[0] = -BOUNDF;
#pragma unroll
        for (int j = 1; j < KBINS; j++) {
            float wj = MIN_BHf + (1.0f - MIN_BHf * (float)KBINS) * (u[j - 1] * inv);
            cum += wj;
            ch[j] = 2.0f * BOUNDF * cum - BOUNDF;
        }
        ch[KBINS] = BOUNDF;
    }
    {
        dv[0] = 1.0f;
        dv[KBINS] = 1.0f;
#pragma unroll
        for (int j = 1; j < KBINS; j++) {
            float v = ud[f * (KBINS - 1) + (j - 1)];
            float sp = fmaxf(v, 0.0f) + log1pf(expf(-fabsf(v))); // stable softplus
            dv[j] = MIN_Df + sp;
        }
    }
    // even knots cw[2],cw[4],...,cw[14] -> rows 0..6 ; odd knots cw[1],cw[3],...,cw[15] -> rows 7..14
#pragma unroll
    for (int j = 0; j < 7; j++) tab[R_KN + j * 256 + f] = cw[2 * j + 2];
#pragma unroll
    for (int p = 0; p < 8; p++) tab[R_KN + (7 + p) * 256 + f] = cw[2 * p + 1];
    // packed per-bin params, BIN-MAJOR: [bin][feature]
    float4* P0g = (float4*)(tab + R_P0);
    float4* P1g = (float4*)(tab + R_P1);
#pragma unroll
    for (int i = 0; i < KBINS; i++) {
        float w = cw[i + 1] - cw[i];
        float binv = 1.0f / w;
        float hb = ch[i + 1] - ch[i];
        float delta = hb * binv;
        float4 p0, p1;
        p0.x = cw[i] * binv;
        p0.y = binv;
        p0.z = hb * delta;
        p0.w = hb * dv[i];
        p1.x = dv[i] + dv[i + 1] - 2.0f * delta;
        p1.y = delta;
        p1.z = ch[i];
        p1.w = 0.0f;
        P0g[i * 256 + f] = p0;
        P1g[i * 256 + f] = p1;
    }
}

// Even/odd split scan + rational-quadratic eval.
// kc[0..6] = cw[2,4..14] in registers; knO LDS [8][32]: knO[p][l] = cw[2p+1].
// idx = 2p + (xn >= cw[2p+1]) == linear 15-count (cw strictly increasing).
__device__ __forceinline__ float eval_rq(float xv, float a, float nb,
                                         const float4* __restrict__ sP0,
                                         const float4* __restrict__ sP1,
                                         const float kc[7],
                                         const float* __restrict__ knO, int l) {
    float xn = fmaf(xv, a, nb);
    int p = 0;
#pragma unroll
    for (int j = 0; j < 7; j++) p += (xn >= kc[j]) ? 1 : 0;
    float ko = knO[(p << 5) | l];
    int idx = (p << 1) + ((xn >= ko) ? 1 : 0);
    int o = (idx << 5) | l;
    float4 p0 = sP0[o];
    float4 p1 = sP1[o];
    float th = fmaf(xn, p0.y, -p0.x);
    float th2 = th * th;
    float t1m = th - th2;
    float numer = fmaf(p0.z, th2, p0.w * t1m);
    float denom = fmaf(p1.x, t1m, p1.y);
    float s = fmaf(numer, __builtin_amdgcn_rcpf(denom), p1.z);
    return (fabsf(xn) < BOUNDF) ? s : xn;
}

template <bool STORE_S>
__global__ __launch_bounds__(256, 6) void k_pass1(const float* __restrict__ X,
                                                  const float* __restrict__ shiftp,
                                                  const float* __restrict__ scalep,
                                                  float* __restrict__ tab,
                                                  unsigned short* __restrict__ S) {
    __shared__ float4 sP0[16 * FTB];
    __shared__ float4 sP1[16 * FTB];
    __shared__ float knO[8 * FTB];
    __shared__ float red[2][SLOTB][FTB];
    int t = threadIdx.x;
    int rb = blockIdx.x, ft = blockIdx.y;
    const float4* P0g = (const float4*)(tab + R_P0);
    const float4* P1g = (const float4*)(tab + R_P1);
    for (int s = t; s < 16 * FTB; s += 256) {
        int bin = s >> 5, li = s & 31;
        sP0[s] = P0g[bin * 256 + ft * FTB + li];
        sP1[s] = P1g[bin * 256 + ft * FTB + li];
    }
    // odd-knot LDS table: 8*32 = 256 entries, one per thread
    knO[t] = tab[R_KN + (7 + (t >> 5)) * 256 + ft * FTB + (t & 31)];
    int l = t & 31, slot = t >> 5;
    int f = ft * FTB + l;
    float kc[7];
#pragma unroll
    for (int j = 0; j < 7; j++) kc[j] = tab[R_KN + j * 256 + f];
    float a = 1.0f / scalep[f];
    float nb = -shiftp[f] * a;
    __syncthreads();
    size_t base = ((size_t)rb * ROWS_PB + slot) * FEAT + f;
    const float* Xp = X + base;
    unsigned short* Sp = STORE_S ? (S + base) : nullptr;
    float sum = 0.f, sumsq = 0.f;
    for (int r = 0; r < ITERB; r += 8) {
        float xv[8];
#pragma unroll
        for (int i = 0; i < 8; i++) xv[i] = Xp[i * SLOTB * FEAT];
        Xp += 8 * SLOTB * FEAT;
        float sv[8];
#pragma unroll
        for (int i = 0; i < 8; i++) sv[i] = eval_rq(xv[i], a, nb, sP0, sP1, kc, knO, l);
        if (STORE_S) {
#pragma unroll
            for (int i = 0; i < 8; i++) Sp[i * SLOTB * FEAT] = __half_as_ushort(__float2half(sv[i]));
            Sp += 8 * SLOTB * FEAT;
        }
#pragma unroll
        for (int i = 0; i < 8; i++) { sum += sv[i]; sumsq = fmaf(sv[i], sv[i], sumsq); }
    }
    red[0][slot][l] = sum;
    red[1][slot][l] = sumsq;
    __syncthreads();
    if (t < FTB) {
        float v = 0.f;
#pragma unroll
        for (int s2i = 0; s2i < SLOTB; s2i++) v += red[0][s2i][t];
        tab[R_PS + (ft * RBB + rb) * FTB + t] = v;
    } else if (t < 2 * FTB) {
        int u = t - FTB;
        float v = 0.f;
#pragma unroll
        for (int s2i = 0; s2i < SLOTB; s2i++) v += red[1][s2i][u];
        tab[R_PS2 + (ft * RBB + rb) * FTB + u] = v;
    }
}

__global__ __launch_bounds__(256) void k_reduce(float* __restrict__ tab) {
    int f = blockIdx.x;
    int ft = f >> 5, l = f & 31;
    int t = threadIdx.x;
    __shared__ float r1[256], r2[256];
    r1[t] = tab[R_PS + (ft * RBB + t) * FTB + l];
    r2[t] = tab[R_PS2 + (ft * RBB + t) * FTB + l];
    __syncthreads();
    for (int off = 128; off > 0; off >>= 1) {
        if (t < off) { r1[t] += r1[t + off]; r2[t] += r2[t + off]; }
        __syncthreads();
    }
    if (t == 0) {
        float mean = r1[0] * (1.0f / (float)BATCH);
        float var = r2[0] * (1.0f / (float)BATCH) - mean * mean;
        var = fmaxf(var, 0.0f);
        tab[R_MEAN + f] = mean;
        tab[R_ISTD + f] = 1.0f / sqrtf(var + EPSF);
    }
}

// Streaming standardize: z = s*istd - mean*istd, s from f16 buffer.
__global__ __launch_bounds__(256, 8) void k_pass2_stream(const unsigned short* __restrict__ S,
                                                         const float* __restrict__ tab,
                                                         float* __restrict__ Z) {
    int gid = blockIdx.x * 256 + threadIdx.x;   // 524288 threads
    int fg = gid & 31;                          // feature-group: features fg*8 .. fg*8+7
    int rs = gid >> 5;                          // row-slot: rows rs*8 .. rs*8+7
    const float* meanp = tab + R_MEAN + fg * 8;
    const float* istdp = tab + R_ISTD + fg * 8;
    float istd[8], nmi[8];
#pragma unroll
    for (int j = 0; j < 8; j++) {
        float m = meanp[j];
        float is = istdp[j];
        istd[j] = is;
        nmi[j] = -m * is;
    }
    size_t idx = (size_t)rs * 8 * FEAT + fg * 8;
#pragma unroll
    for (int r = 0; r < 8; r++) {
        uint4 sv = *(const uint4*)(S + idx);
        float2 f0 = __half22float2(*(const __half2*)&sv.x);
        float2 f1 = __half22float2(*(const __half2*)&sv.y);
        float2 f2 = __half22float2(*(const __half2*)&sv.z);
        float2 f3 = __half22float2(*(const __half2*)&sv.w);
        float z0 = fmaf(f0.x, istd[0], nmi[0]);
        float z1 = fmaf(f0.y, istd[1], nmi[1]);
        float z2 = fmaf(f1.x, istd[2], nmi[2]);
        float z3 = fmaf(f1.y, istd[3], nmi[3]);
        float z4 = fmaf(f2.x, istd[4], nmi[4]);
        float z5 = fmaf(f2.y, istd[5], nmi[5]);
        float z6 = fmaf(f3.x, istd[6], nmi[6]);
        float z7 = fmaf(f3.y, istd[7], nmi[7]);
        float4* Zp = (float4*)(Z + idx);
        Zp[0] = make_float4(z0, z1, z2, z3);
        Zp[1] = make_float4(z4, z5, z6, z7);
        idx += FEAT;
    }
}

// Fallback pass2: recompute spline (when ws can't hold S).
__global__ __launch_bounds__(256, 6) void k_pass2_eval(const float* __restrict__ X,
                                                       const float* __restrict__ shiftp,
                                                       const float* __restrict__ scalep,
                                                       const float* __restrict__ tab,
                                                       float* __restrict__ Z) {
    __shared__ float4 sP0[16 * FTB];
    __shared__ float4 sP1[16 * FTB];
    __shared__ float knO[8 * FTB];
    int t = threadIdx.x;
    int rb = blockIdx.x, ft = blockIdx.y;
    const float4* P0g = (const float4*)(tab + R_P0);
    const float4* P1g = (const float4*)(tab + R_P1);
    for (int s = t; s < 16 * FTB; s += 256) {
        int bin = s >> 5, li = s & 31;
        sP0[s] = P0g[bin * 256 + ft * FTB + li];
        sP1[s] = P1g[bin * 256 + ft * FTB + li];
    }
    knO[t] = tab[R_KN + (7 + (t >> 5)) * 256 + ft * FTB + (t & 31)];
    int l = t & 31, slot = t >> 5;
    int f = ft * FTB + l;
    float kc[7];
#pragma unroll
    for (int j = 0; j < 7; j++) kc[j] = tab[R_KN + j * 256 + f];
    float a = 1.0f / scalep[f];
    float nb = -shiftp[f] * a;
    float mean = tab[R_MEAN + f];
    float istd = tab[R_ISTD + f];
    __syncthreads();
    size_t base = ((size_t)rb * ROWS_PB + slot) * FEAT + f;
    const float* Xp = X + base;
    float* Zp = Z + base;
    for (int r = 0; r < ITERB; r += 4) {
        float x0 = Xp[0 * SLOTB * FEAT];
        float x1 = Xp[1 * SLOTB * FEAT];
        float x2 = Xp[2 * SLOTB * FEAT];
        float x3 = Xp[3 * SLOTB * FEAT];
        Xp += 4 * SLOTB * FEAT;
        float s0 = eval_rq(x0, a, nb, sP0, sP1, kc, knO, l);
        float s1 = eval_rq(x1, a, nb, sP0, sP1, kc, knO, l);
        float s2 = eval_rq(x2, a, nb, sP0, sP1, kc, knO, l);
        float s3 = eval_rq(x3, a, nb, sP0, sP1, kc, knO, l);
        Zp[0 * SLOTB * FEAT] = (s0 - mean) * istd;
        Zp[1 * SLOTB * FEAT] = (s1 - mean) * istd;
        Zp[2 * SLOTB * FEAT] = (s2 - mean) * istd;
        Zp[3 * SLOTB * FEAT] = (s3 - mean) * istd;
        Zp += 4 * SLOTB * FEAT;
    }
}

extern "C" void kernel_launch(void* const* d_in, const int* in_sizes, int n_in,
                              void* d_out, int out_size, void* d_ws, size_t ws_size,
                              hipStream_t stream) {
    const float* x     = (const float*)d_in[0];
    const float* uw    = (const float*)d_in[1];
    const float* uh    = (const float*)d_in[2];
    const float* ud    = (const float*)d_in[3];
    const float* shift = (const float*)d_in[4];
    const float* scale = (const float*)d_in[5];
    float* out = (float*)d_out;
    float* ws  = (float*)d_ws;

    size_t need = (S_FLOATS + (size_t)TAB_FLOATS) * sizeof(float);
    bool useS = ws_size >= need;
    float* tab = ws + (useS ? S_FLOATS : 0);
    unsigned short* S = (unsigned short*)ws;

    k_params<<<1, 256, 0, stream>>>(uw, uh, ud, tab);
    if (useS) {
        k_pass1<true><<<dim3(RBB, FT_TILES), 256, 0, stream>>>(x, shift, scale, tab, S);
        k_reduce<<<FEAT, 256, 0, stream>>>(tab);
        k_pass2_stream<<<2048, 256, 0, stream>>>(S, tab, out);
    } else {
        k_pass1<false><<<dim3(RBB, FT_TILES), 256, 0, stream>>>(x, shift, scale, tab, nullptr);
        k_reduce<<<FEAT, 256, 0, stream>>>(tab);
        k_pass2_eval<<<dim3(RBB, FT_TILES), 256, 0, stream>>>(x, shift, scale, tab, out);
    }
}

// Round 13
// 109.395 us; speedup vs baseline: 1.0571x; 1.0345x over previous
//
#include <hip/hip_runtime.h>
#include <hip/hip_fp16.h>
#include <math.h>

// MonotoneFeatureTransform: rational-quadratic spline per feature + batch standardize.
// B=131072, F=256, K=16. f32 in/out.
// pass1: R10 frame (FTB=32, SLOTB=8, batch-8, bin-major LDS [16][32] float4 = 0
//   conflicts, lb(256,6), linear 15-compare register scan, f16 spill).
//   R13 delta: explicit issue/consume software pipeline in half-batches of 4 —
//   scan (pure VALU) -> issue 8 ds_read_b128 into staging regs -> consume.
//   One lgkmcnt wait covers 8 reads instead of per-element read->use.
// BANNED (measured): nested-ternary select trees (R9), lb(256,8)/plain-lb
//   (R4/R7/R8 VGPR-24 collapse), any data-dependent LDS read before the table
//   read (R11 4-level, R12 even/odd: latency chain, VALU 52->32-36%).
// pass2: streaming standardize from f16 spill.

#define FEAT 256
#define KBINS 16
#define BATCH 131072
#define BOUNDF 5.0f
#define MIN_Df 1e-3f
#define MIN_BWf 1e-3f
#define MIN_BHf 1e-3f
#define EPSF 1e-8f

#define FTB 32                 // features per tile
#define FT_TILES 8
#define SLOTB 8                // row slots per block (256 thr / 32 feat)
#define RBB 256                // row-blocks
#define ROWS_PB (BATCH / RBB)  // 512 rows per block
#define ITERB (ROWS_PB / SLOTB) // 64 rows per thread

// Table region, float offsets relative to `tab`.
#define R_P0   0                    // [16][256] float4: cw0*binv, binv, h*delta, h*d0
#define R_P1   16384                // [16][256] float4: dsum, delta, ch0, pad
#define R_KN   32768                // [15][256] interior knots (cw[1..15])
#define R_MEAN 36608                // [256]
#define R_ISTD 36864                // [256]
#define R_PS   37120                // [2048][32] partial sums
#define R_PS2  (R_PS + 2048 * 32)   // [2048][32] partial sumsq
#define TAB_FLOATS (R_PS2 + 2048 * 32)
#define S_ELEMS ((size_t)BATCH * FEAT)
#define S_FLOATS (S_ELEMS / 2)

__global__ __launch_bounds__(256) void k_params(const float* __restrict__ uw,
                                                const float* __restrict__ uh,
                                                const float* __restrict__ ud,
                                                float* __restrict__ tab) {
    int f = threadIdx.x;
    float cw[17], ch[17], dv[17];
    {
        float u[KBINS];
#pragma unroll
        for (int j = 0; j < KBINS; j++) u[j] = uw[f * KBINS + j];
        float m = u[0];
#pragma unroll
        for (int j = 1; j < KBINS; j++) m = fmaxf(m, u[j]);
        float ssum = 0.f;
#pragma unroll
        for (int j = 0; j < KBINS; j++) { u[j] = expf(u[j] - m); ssum += u[j]; }
        float inv = 1.0f / ssum;
        float cum = 0.f;
        cw[0] = -BOUNDF;
#pragma unroll
        for (int j = 1; j < KBINS; j++) {
            float wj = MIN_BWf + (1.0f - MIN_BWf * (float)KBINS) * (u[j - 1] * inv);
            cum += wj;
            cw[j] = 2.0f * BOUNDF * cum - BOUNDF;
        }
        cw[KBINS] = BOUNDF;
    }
    {
        float u[KBINS];
#pragma unroll
        for (int j = 0; j < KBINS; j++) u[j] = uh[f * KBINS + j];
        float m = u[0];
#pragma unroll
        for (int j = 1; j < KBINS; j++) m = fmaxf(m, u[j]);
        float ssum = 0.f;
#pragma unroll
        for (int j = 0; j < KBINS; j++) { u[j] = expf(u[j] - m); ssum += u[j]; }
        float inv = 1.0f / ssum;
        float cum = 0.f;
        ch[0] = -BOUNDF;
#pragma unroll
        for (int j = 1; j < KBINS; j++) {
            float wj = MIN_BHf + (1.0f - MIN_BHf * (float)KBINS) * (u[j - 1] * inv);
            cum += wj;
            ch[j] = 2.0f * BOUNDF * cum - BOUNDF;
        }
        ch[KBINS] = BOUNDF;
    }
    {
        dv[0] = 1.0f;
        dv[KBINS] = 1.0f;
#pragma unroll
        for (int j = 1; j < KBINS; j++) {
            float v = ud[f * (KBINS - 1) + (j - 1)];
            float sp = fmaxf(v, 0.0f) + log1pf(expf(-fabsf(v))); // stable softplus
            dv[j] = MIN_Df + sp;
        }
    }
    // interior knots, feature-minor for coalesced reads
#pragma unroll
    for (int j = 0; j < 15; j++) tab[R_KN + j * 256 + f] = cw[j + 1];
    // packed per-bin params, BIN-MAJOR: [bin][feature]
    float4* P0g = (float4*)(tab + R_P0);
    float4* P1g = (float4*)(tab + R_P1);
#pragma unroll
    for (int i = 0; i < KBINS; i++) {
        float w = cw[i + 1] - cw[i];
        float binv = 1.0f / w;
        float hb = ch[i + 1] - ch[i];
        float delta = hb * binv;
        float4 p0, p1;
        p0.x = cw[i] * binv;
        p0.y = binv;
        p0.z = hb * delta;
        p0.w = hb * dv[i];
        p1.x = dv[i] + dv[i + 1] - 2.0f * delta;
        p1.y = delta;
        p1.z = ch[i];
        p1.w = 0.0f;
        P0g[i * 256 + f] = p0;
        P1g[i * 256 + f] = p1;
    }
}

// Linear 15-compare scan -> table offset (no LDS reads inside).
__device__ __forceinline__ int scan_idx(float xn, const float kn[15], int l) {
    int idx = 0;
#pragma unroll
    for (int j = 0; j < 15; j++) idx += (xn >= kn[j]) ? 1 : 0;
    return (idx << 5) | l;
}

// Rational-quadratic finish from staged table params.
__device__ __forceinline__ float rq_finish(float xn, float4 p0, float4 p1) {
    float th = fmaf(xn, p0.y, -p0.x);
    float th2 = th * th;
    float t1m = th - th2;
    float numer = fmaf(p0.z, th2, p0.w * t1m);
    float denom = fmaf(p1.x, t1m, p1.y);
    float s = fmaf(numer, __builtin_amdgcn_rcpf(denom), p1.z);
    return (fabsf(xn) < BOUNDF) ? s : xn;
}

template <bool STORE_S>
__global__ __launch_bounds__(256, 6) void k_pass1(const float* __restrict__ X,
                                                  const float* __restrict__ shiftp,
                                                  const float* __restrict__ scalep,
                                                  float* __restrict__ tab,
                                                  unsigned short* __restrict__ S) {
    __shared__ float4 sP0[16 * FTB];
    __shared__ float4 sP1[16 * FTB];
    __shared__ float red[2][SLOTB][FTB];
    int t = threadIdx.x;
    int rb = blockIdx.x, ft = blockIdx.y;
    const float4* P0g = (const float4*)(tab + R_P0);
    const float4* P1g = (const float4*)(tab + R_P1);
    for (int s = t; s < 16 * FTB; s += 256) {
        int bin = s >> 5, li = s & 31;
        sP0[s] = P0g[bin * 256 + ft * FTB + li];
        sP1[s] = P1g[bin * 256 + ft * FTB + li];
    }
    int l = t & 31, slot = t >> 5;
    int f = ft * FTB + l;
    float kn[15];
#pragma unroll
    for (int j = 0; j < 15; j++) kn[j] = tab[R_KN + j * 256 + f];
    float a = 1.0f / scalep[f];
    float nb = -shiftp[f] * a;
    __syncthreads();
    size_t base = ((size_t)rb * ROWS_PB + slot) * FEAT + f;
    const float* Xp = X + base;
    unsigned short* Sp = STORE_S ? (S + base) : nullptr;
    float sum = 0.f, sumsq = 0.f;
    for (int r = 0; r < ITERB; r += 8) {
        float xv[8];
#pragma unroll
        for (int i = 0; i < 8; i++) xv[i] = Xp[i * SLOTB * FEAT];
        Xp += 8 * SLOTB * FEAT;
        float sv[8];
#pragma unroll
        for (int h = 0; h < 2; h++) {
            // stage 1: pure-VALU scan for 4 elements
            float xn[4]; int oo[4];
#pragma unroll
            for (int i = 0; i < 4; i++) {
                xn[i] = fmaf(xv[h * 4 + i], a, nb);
                oo[i] = scan_idx(xn[i], kn, l);
            }
            // stage 2: issue all 8 ds_read_b128
            float4 q0[4], q1[4];
#pragma unroll
            for (int i = 0; i < 4; i++) { q0[i] = sP0[oo[i]]; q1[i] = sP1[oo[i]]; }
            // stage 3: consume
#pragma unroll
            for (int i = 0; i < 4; i++) sv[h * 4 + i] = rq_finish(xn[i], q0[i], q1[i]);
        }
        if (STORE_S) {
#pragma unroll
            for (int i = 0; i < 8; i++) Sp[i * SLOTB * FEAT] = __half_as_ushort(__float2half(sv[i]));
            Sp += 8 * SLOTB * FEAT;
        }
#pragma unroll
        for (int i = 0; i < 8; i++) { sum += sv[i]; sumsq = fmaf(sv[i], sv[i], sumsq); }
    }
    red[0][slot][l] = sum;
    red[1][slot][l] = sumsq;
    __syncthreads();
    if (t < FTB) {
        float v = 0.f;
#pragma unroll
        for (int s2i = 0; s2i < SLOTB; s2i++) v += red[0][s2i][t];
        tab[R_PS + (ft * RBB + rb) * FTB + t] = v;
    } else if (t < 2 * FTB) {
        int u = t - FTB;
        float v = 0.f;
#pragma unroll
        for (int s2i = 0; s2i < SLOTB; s2i++) v += red[1][s2i][u];
        tab[R_PS2 + (ft * RBB + rb) * FTB + u] = v;
    }
}

__global__ __launch_bounds__(256) void k_reduce(float* __restrict__ tab) {
    int f = blockIdx.x;
    int ft = f >> 5, l = f & 31;
    int t = threadIdx.x;
    __shared__ float r1[256], r2[256];
    r1[t] = tab[R_PS + (ft * RBB + t) * FTB + l];
    r2[t] = tab[R_PS2 + (ft * RBB + t) * FTB + l];
    __syncthreads();
    for (int off = 128; off > 0; off >>= 1) {
        if (t < off) { r1[t] += r1[t + off]; r2[t] += r2[t + off]; }
        __syncthreads();
    }
    if (t == 0) {
        float mean = r1[0] * (1.0f / (float)BATCH);
        float var = r2[0] * (1.0f / (float)BATCH) - mean * mean;
        var = fmaxf(var, 0.0f);
        tab[R_MEAN + f] = mean;
        tab[R_ISTD + f] = 1.0f / sqrtf(var + EPSF);
    }
}

// Streaming standardize: z = s*istd - mean*istd, s from f16 buffer.
__global__ __launch_bounds__(256, 8) void k_pass2_stream(const unsigned short* __restrict__ S,
                                                         const float* __restrict__ tab,
                                                         float* __restrict__ Z) {
    int gid = blockIdx.x * 256 + threadIdx.x;   // 524288 threads
    int fg = gid & 31;                          // feature-group: features fg*8 .. fg*8+7
    int rs = gid >> 5;                          // row-slot: rows rs*8 .. rs*8+7
    const float* meanp = tab + R_MEAN + fg * 8;
    const float* istdp = tab + R_ISTD + fg * 8;
    float istd[8], nmi[8];
#pragma unroll
    for (int j = 0; j < 8; j++) {
        float m = meanp[j];
        float is = istdp[j];
        istd[j] = is;
        nmi[j] = -m * is;
    }
    size_t idx = (size_t)rs * 8 * FEAT + fg * 8;
#pragma unroll
    for (int r = 0; r < 8; r++) {
        uint4 sv = *(const uint4*)(S + idx);
        float2 f0 = __half22float2(*(const __half2*)&sv.x);
        float2 f1 = __half22float2(*(const __half2*)&sv.y);
        float2 f2 = __half22float2(*(const __half2*)&sv.z);
        float2 f3 = __half22float2(*(const __half2*)&sv.w);
        float z0 = fmaf(f0.x, istd[0], nmi[0]);
        float z1 = fmaf(f0.y, istd[1], nmi[1]);
        float z2 = fmaf(f1.x, istd[2], nmi[2]);
        float z3 = fmaf(f1.y, istd[3], nmi[3]);
        float z4 = fmaf(f2.x, istd[4], nmi[4]);
        float z5 = fmaf(f2.y, istd[5], nmi[5]);
        float z6 = fmaf(f3.x, istd[6], nmi[6]);
        float z7 = fmaf(f3.y, istd[7], nmi[7]);
        float4* Zp = (float4*)(Z + idx);
        Zp[0] = make_float4(z0, z1, z2, z3);
        Zp[1] = make_float4(z4, z5, z6, z7);
        idx += FEAT;
    }
}

// Fallback pass2: recompute spline (when ws can't hold S).
__global__ __launch_bounds__(256, 6) void k_pass2_eval(const float* __restrict__ X,
                                                       const float* __restrict__ shiftp,
                                                       const float* __restrict__ scalep,
                                                       const float* __restrict__ tab,
                                                       float* __restrict__ Z) {
    __shared__ float4 sP0[16 * FTB];
    __shared__ float4 sP1[16 * FTB];
    int t = threadIdx.x;
    int rb = blockIdx.x, ft = blockIdx.y;
    const float4* P0g = (const float4*)(tab + R_P0);
    const float4* P1g = (const float4*)(tab + R_P1);
    for (int s = t; s < 16 * FTB; s += 256) {
        int bin = s >> 5, li = s & 31;
        sP0[s] = P0g[bin * 256 + ft * FTB + li];
        sP1[s] = P1g[bin * 256 + ft * FTB + li];
    }
    int l = t & 31, slot = t >> 5;
    int f = ft * FTB + l;
    float kn[15];
#pragma unroll
    for (int j = 0; j < 15; j++) kn[j] = tab[R_KN + j * 256 + f];
    float a = 1.0f / scalep[f];
    float nb = -shiftp[f] * a;
    float mean = tab[R_MEAN + f];
    float istd = tab[R_ISTD + f];
    __syncthreads();
    size_t base = ((size_t)rb * ROWS_PB + slot) * FEAT + f;
    const float* Xp = X + base;
    float* Zp = Z + base;
    for (int r = 0; r < ITERB; r += 4) {
        float x0 = Xp[0 * SLOTB * FEAT];
        float x1 = Xp[1 * SLOTB * FEAT];
        float x2 = Xp[2 * SLOTB * FEAT];
        float x3 = Xp[3 * SLOTB * FEAT];
        Xp += 4 * SLOTB * FEAT;
        float xn0 = fmaf(x0, a, nb), xn1 = fmaf(x1, a, nb);
        float xn2 = fmaf(x2, a, nb), xn3 = fmaf(x3, a, nb);
        int o0 = scan_idx(xn0, kn, l), o1 = scan_idx(xn1, kn, l);
        int o2 = scan_idx(xn2, kn, l), o3 = scan_idx(xn3, kn, l);
        float s0 = rq_finish(xn0, sP0[o0], sP1[o0]);
        float s1 = rq_finish(xn1, sP0[o1], sP1[o1]);
        float s2 = rq_finish(xn2, sP0[o2], sP1[o2]);
        float s3 = rq_finish(xn3, sP0[o3], sP1[o3]);
        Zp[0 * SLOTB * FEAT] = (s0 - mean) * istd;
        Zp[1 * SLOTB * FEAT] = (s1 - mean) * istd;
        Zp[2 * SLOTB * FEAT] = (s2 - mean) * istd;
        Zp[3 * SLOTB * FEAT] = (s3 - mean) * istd;
        Zp += 4 * SLOTB * FEAT;
    }
}

extern "C" void kernel_launch(void* const* d_in, const int* in_sizes, int n_in,
                              void* d_out, int out_size, void* d_ws, size_t ws_size,
                              hipStream_t stream) {
    const float* x     = (const float*)d_in[0];
    const float* uw    = (const float*)d_in[1];
    const float* uh    = (const float*)d_in[2];
    const float* ud    = (const float*)d_in[3];
    const float* shift = (const float*)d_in[4];
    const float* scale = (const float*)d_in[5];
    float* out = (float*)d_out;
    float* ws  = (float*)d_ws;

    size_t need = (S_FLOATS + (size_t)TAB_FLOATS) * sizeof(float);
    bool useS = ws_size >= need;
    float* tab = ws + (useS ? S_FLOATS : 0);
    unsigned short* S = (unsigned short*)ws;

    k_params<<<1, 256, 0, stream>>>(uw, uh, ud, tab);
    if (useS) {
        k_pass1<true><<<dim3(RBB, FT_TILES), 256, 0, stream>>>(x, shift, scale, tab, S);
        k_reduce<<<FEAT, 256, 0, stream>>>(tab);
        k_pass2_stream<<<2048, 256, 0, stream>>>(S, tab, out);
    } else {
        k_pass1<false><<<dim3(RBB, FT_TILES), 256, 0, stream>>>(x, shift, scale, tab, nullptr);
        k_reduce<<<FEAT, 256, 0, stream>>>(tab);
        k_pass2_eval<<<dim3(RBB, FT_TILES), 256, 0, stream>>>(x, shift, scale, tab, out);
    }
}